// Round 14
// baseline (379.242 us; speedup 1.0000x reference)
//
#include <hip/hip_runtime.h>
#include <hip/hip_bf16.h>

typedef __attribute__((ext_vector_type(8))) short s8;   // 8 bf16 = 4 VGPRs
typedef __attribute__((ext_vector_type(4))) float f4;

#define TILE 128

// gelu tanh-approx (JAX approximate=True), exp2-folded
__device__ __forceinline__ float gelu_fast(float x) {
    float x2 = x * x;
    float k2 = x * fmaf(x2, 0.10294326f, 2.30220819f);
    float e  = __builtin_amdgcn_exp2f(k2);
    float r  = __builtin_amdgcn_rcpf(e + 1.f);
    return fmaf(-x, r, x);
}

// round-half-up f32->bf16 pair pack: 3 VALU [numerics validated R10-R13]
__device__ __forceinline__ unsigned pack_bf16x2_fast(float a, float b) {
    unsigned ua = __builtin_bit_cast(unsigned, a) + 0x8000u;
    unsigned ub = __builtin_bit_cast(unsigned, b) + 0x8000u;
    return __builtin_amdgcn_perm(ub, ua, 0x07060302u);
}

__device__ __forceinline__ short f2bf_bits(float v) {
    __hip_bfloat16 b = __float2bfloat16(v);
    return *(short*)&b;
}

// ---------------- fused prep: zero + pack_w2 + rowptr x4 + lift/W0 matmul ----
struct PrepArgs {
    float* zbase; long zn4;                       // zero range (f4 units)
    const float* w2s[4]; short* w2pack;           // pack
    const int* edst[4]; int E[4]; int N[4]; int* rowptr[4]; int rbPer;
    const float *samples, *LW, *Lb, *W0, *W0b;    // lift + W0 matmul
    float *vout, *w0t;
    int zb;                                       // zero block count
};

__global__ __launch_bounds__(256) void prep_kernel(PrepArgs A) {
    __shared__ float s_x[16 * 128];
    int bid = blockIdx.x;
    const int t = threadIdx.x;
    if (bid < A.zb) {                     // ---- zero acc00+acc01
        long i = (long)bid * 256 + t;
        if (i < A.zn4) { f4 z = {0.f, 0.f, 0.f, 0.f}; *(f4*)&A.zbase[i * 4] = z; }
        return;
    }
    bid -= A.zb;
    if (bid < 16) {                       // ---- pack w2 (graph = bid>>2, T = bid&3)
        if (t < 128) {
            const int g = bid >> 2, T = bid & 3;
            const float* w2 = A.w2s[g];
            short* dst = A.w2pack + (size_t)g * 8192;
            const int w = t >> 6, lane = t & 63, q = (lane >> 4), n = lane & 15;
#pragma unroll
            for (int s = 0; s < 2; ++s)
#pragma unroll
                for (int j = 0; j < 8; ++j) {
                    int k  = s * 32 + q * 8 + j;
                    int ch = 64 * w + 4 * n + T;
                    dst[((((w * 4 + T) * 2 + s) * 64) + lane) * 8 + j] =
                        f2bf_bits(w2[k * 128 + ch]);
                }
        }
        return;
    }
    bid -= 16;
    if (bid < 4 * A.rbPer) {              // ---- rowptr for 4 graphs
        const int g = bid / A.rbPer;
        const int i = (bid % A.rbPer) * 256 + t;
        const int* ed = A.edst[g]; const int E = A.E[g]; const int N = A.N[g];
        int* rp = A.rowptr[g];
        if (i < E) {
            int dd = ed[i];
            int p  = (i == 0) ? -1 : ed[i - 1];
            for (int r = p + 1; r <= dd; ++r) rp[r] = i;
            if (i == E - 1)
                for (int r = dd + 1; r <= N; ++r) rp[r] = E;
        }
        return;
    }
    bid -= 4 * A.rbPer;
    // ---- lift + W0 matmul, 16 rows per block, 256 threads
    {
        const int r0 = bid * 16;
        const int col = t & 127, half = t >> 7;
#pragma unroll
        for (int j = 0; j < 8; ++j) {
            int r = r0 + half * 8 + j;
            float s0 = A.samples[r * 3 + 0], s1 = A.samples[r * 3 + 1], s2 = A.samples[r * 3 + 2];
            float v = s0 * A.LW[col] + s1 * A.LW[128 + col] + s2 * A.LW[256 + col] + A.Lb[col];
            s_x[(half * 8 + j) * 128 + col] = v;
            A.vout[(long)r * 128 + col] = v;
        }
        __syncthreads();
        float acc[8];
        const float bc = A.W0b[col];
#pragma unroll
        for (int j = 0; j < 8; ++j) acc[j] = bc;
#pragma unroll 4
        for (int hh = 0; hh < 128; ++hh) {
            float wv = A.W0[hh * 128 + col];
#pragma unroll
            for (int j = 0; j < 8; ++j) acc[j] += s_x[(half * 8 + j) * 128 + hh] * wv;
        }
#pragma unroll
        for (int j = 0; j < 8; ++j)
            A.w0t[(long)(r0 + half * 8 + j) * 128 + col] = acc[j];
    }
}

// ---------------- gno: R9 flush/layout + 32-edge superwindow, SINGLE-buffer --
struct GnoP {
    const float* fy;
    const int* esrc;
    const int* edst;
    const float* w1;
    const float* b1;
    const short* w2;
    const float* b2;
    float* acc;
    int E, sx, sy, pad;
};

__device__ __forceinline__ int seg_end(unsigned long long m0, unsigned long long m1, int a) {
    if (a < 64) {
        unsigned long long r = m0 >> a;
        if (r) return a + (int)__builtin_ctzll(r) + 1;
        return 64 + (int)__builtin_ctzll(m1) + 1;
    }
    unsigned long long r = m1 >> (a - 64);
    return a + (int)__builtin_ctzll(r) + 1;
}

// 2-wave blocks, 128 edges/tile, 32-edge superwindows with SINGLE-buffered
// s_gb (LDS ~= R9's 8.2 KB => occupancy preserved, unlike R11's dbuf).
// 2 barriers per superwindow = R9's barrier rate, half the loop overhead.
__global__ __launch_bounds__(128) void gno_edge_kernel(
    const float* __restrict__ coords, int n0, GnoP A, GnoP B, int ntA)
{
    const GnoP P = (blockIdx.x < ntA) ? A : B;
    const int tile = (blockIdx.x < ntA) ? blockIdx.x : blockIdx.x - ntA;
    const int t = threadIdx.x;
    const int w = t >> 6, lane = t & 63, q = lane >> 4, n = lane & 15;
    const int e0 = tile * TILE;
    const int te = min(TILE, P.E - e0);

    __shared__ __align__(16) float s_crd[(TILE + 32) * 4];
    __shared__ int s_off[TILE];
    __shared__ int s_dst[TILE];
    __shared__ unsigned long long s_mask[2];
    __shared__ __align__(16) short s_gb[32 * 72];   // single buffer

    // stage edge t (+32 pad rows with any finite coords)
    {
        int e = min(e0 + t, P.E - 1);
        int sv = P.esrc[e];
        int dv = P.edst[e];
        s_off[t] = sv * 128;
        s_dst[t] = dv;
        f4 c4 = {coords[(long)sv * P.sy], coords[n0 + (long)sv * P.sy],
                 coords[(long)dv * P.sx], coords[n0 + (long)dv * P.sx]};
        *(f4*)&s_crd[t * 4] = c4;
        if (t < 32) *(f4*)&s_crd[(TILE + t) * 4] = c4;
    }

    const int h0 = 2 * (lane & 31);
    const float wA0 = P.w1[h0],       wA1 = P.w1[h0 + 1];
    const float wB0 = P.w1[64 + h0],  wB1 = P.w1[65 + h0];
    const float wC0 = P.w1[128 + h0], wC1 = P.w1[129 + h0];
    const float wD0 = P.w1[192 + h0], wD1 = P.w1[193 + h0];
    const float b10 = P.b1[h0],       b11 = P.b1[h0 + 1];

    s8 bfrag[4][2];
    const s8* w2f = (const s8*)P.w2;
#pragma unroll
    for (int T = 0; T < 4; ++T)
#pragma unroll
        for (int s = 0; s < 2; ++s)
            bfrag[T][s] = w2f[((w * 4 + T) * 2 + s) * 64 + lane];
    const f4 b2c = *(const f4*)&P.b2[w * 64 + 4 * n];
    f4 b2i[4];
#pragma unroll
    for (int T = 0; T < 4; ++T) { f4 z = {b2c[T], b2c[T], b2c[T], b2c[T]}; b2i[T] = z; }

    const float* fyl = P.fy + (w * 64 + 4 * n);

    __syncthreads();

    {
        int idx = w * 64 + lane;
        bool fl = (idx < te) && (idx == te - 1 || s_dst[idx + 1] != s_dst[idx]);
        unsigned long long m = __ballot(fl);
        if (lane == 0) s_mask[w] = m;
    }
    __syncthreads();
    const unsigned long long m0 = s_mask[0], m1 = s_mask[1];

    int g0 = 0;
    int b = seg_end(m0, m1, 0);
    f4 fv0[4], fv1[4];
#pragma unroll
    for (int r = 0; r < 4; ++r) {
        int row0 = q * 4 + r, row1 = 16 + q * 4 + r;
        if (row0 < b) fv0[r] = *(const f4*)&fyl[s_off[row0]];
        else { f4 z = {0.f, 0.f, 0.f, 0.f}; fv0[r] = z; }
        if (row1 < b) fv1[r] = *(const f4*)&fyl[s_off[row1]];
        else { f4 z = {0.f, 0.f, 0.f, 0.f}; fv1[r] = z; }
    }
    f4 accr = {0.f, 0.f, 0.f, 0.f};
    const int jh = lane >> 5;

    while (true) {
        // layer1: 8 pair-iters, j = 4i + 2jh + w covers superwindow rows 0..31
#pragma unroll
        for (int i = 0; i < 8; ++i) {
            int j = 4 * i + 2 * jh + w;
            const f4 crd = *(const f4*)&s_crd[(g0 + j) * 4];
            float x0 = fmaf(crd[0], wA0, fmaf(crd[1], wB0,
                       fmaf(crd[2], wC0, fmaf(crd[3], wD0, b10))));
            float x1 = fmaf(crd[0], wA1, fmaf(crd[1], wB1,
                       fmaf(crd[2], wC1, fmaf(crd[3], wD1, b11))));
            *(unsigned*)&s_gb[j * 72 + h0] = pack_bf16x2_fast(gelu_fast(x0), gelu_fast(x1));
        }
        __syncthreads();   // writes visible to both waves
        const int cnt = min(32, b - g0);
        // sub-block 0: rows 0..15 (b2 via C-init)
        {
            const s8 a0 = *(const s8*)&s_gb[n * 72 + q * 8];
            const s8 a1 = *(const s8*)&s_gb[n * 72 + q * 8 + 32];
            f4 c[4];
#pragma unroll
            for (int T = 0; T < 4; ++T) {
                f4 z = __builtin_amdgcn_mfma_f32_16x16x32_bf16(a0, bfrag[T][0], b2i[T], 0, 0, 0);
                c[T] = __builtin_amdgcn_mfma_f32_16x16x32_bf16(a1, bfrag[T][1], z, 0, 0, 0);
            }
#pragma unroll
            for (int r = 0; r < 4; ++r)
#pragma unroll
                for (int T = 0; T < 4; ++T)
                    accr[T] = fmaf(c[T][r], fv0[r][T], accr[T]);
        }
        // sub-block 1: rows 16..31 (skipped when segment truncates <=16)
        if (cnt > 16) {
            const s8 a0 = *(const s8*)&s_gb[(16 + n) * 72 + q * 8];
            const s8 a1 = *(const s8*)&s_gb[(16 + n) * 72 + q * 8 + 32];
            f4 c[4];
#pragma unroll
            for (int T = 0; T < 4; ++T) {
                f4 z = __builtin_amdgcn_mfma_f32_16x16x32_bf16(a0, bfrag[T][0], b2i[T], 0, 0, 0);
                c[T] = __builtin_amdgcn_mfma_f32_16x16x32_bf16(a1, bfrag[T][1], z, 0, 0, 0);
            }
#pragma unroll
            for (int r = 0; r < 4; ++r)
#pragma unroll
                for (int T = 0; T < 4; ++T)
                    accr[T] = fmaf(c[T][r], fv1[r][T], accr[T]);
        }

        int gn = g0 + cnt, bn = b;
        const bool endseg = (g0 + 32 >= b);
        if (endseg) {
            gn = b;
            if (gn < te) bn = seg_end(m0, m1, gn);
            const int dcur = s_dst[g0];
#pragma unroll
            for (int T = 0; T < 4; ++T) {
                float v = accr[T];
                v += __shfl_xor(v, 16, 64);
                v += __shfl_xor(v, 32, 64);
                if (q == 0)
                    atomicAdd(&P.acc[(long)dcur * 128 + w * 64 + 4 * n + T], v);
            }
            f4 z = {0.f, 0.f, 0.f, 0.f};
            accr = z;
        }
        if (gn >= te) break;
        // reload fv for next superwindow (after last use)
#pragma unroll
        for (int r = 0; r < 4; ++r) {
            int row0 = gn + q * 4 + r, row1 = gn + 16 + q * 4 + r;
            if (row0 < bn) fv0[r] = *(const f4*)&fyl[s_off[row0]];
            else { f4 z = {0.f, 0.f, 0.f, 0.f}; fv0[r] = z; }
            if (row1 < bn) fv1[r] = *(const f4*)&fyl[s_off[row1]];
            else { f4 z = {0.f, 0.f, 0.f, 0.f}; fv1[r] = z; }
        }
        g0 = gn; b = bn;
        __syncthreads();   // all reads done before next layer-1 overwrite
    }
}

// fused: base read = gno01b_raw/deg01; u = relu(accu/deg11 + w1t) (rezero accu);
// vd1 = relu(base_mean [+ u]); w1t = vd1 @ W + bias. it0: accu=null, zbuf zeroed.
__global__ __launch_bounds__(128) void relu_mm_kernel(
    const float* __restrict__ base, const int* __restrict__ rp01,
    float* __restrict__ accu, const int* __restrict__ rowptr,
    float* __restrict__ w1t,
    const float* __restrict__ W, const float* __restrict__ bias,
    float* __restrict__ vout, float* __restrict__ zbuf, int R)
{
    const int r0 = blockIdx.x * 8;
    const int t = threadIdx.x;
    __shared__ float s_x[8 * 128];
#pragma unroll
    for (int j = 0; j < 8; ++j) {
        int r = r0 + j;
        long o = (long)r * 128 + t;
        float deg0 = (float)(rp01[r + 1] - rp01[r]);
        float v = base[o] / fmaxf(deg0, 1.f);
        if (accu) {
            float deg = (float)(rowptr[r + 1] - rowptr[r]);
            float u = fmaxf(accu[o] / fmaxf(deg, 1.f) + w1t[o], 0.f);
            v += u;
            accu[o] = 0.f;
        } else if (zbuf) {
            zbuf[o] = 0.f;
        }
        v = fmaxf(v, 0.f);
        s_x[j * 128 + t] = v;
        vout[o] = v;
    }
    __syncthreads();
    float acc[8];
    const float bc = bias[t];
#pragma unroll
    for (int j = 0; j < 8; ++j) acc[j] = bc;
#pragma unroll 4
    for (int hh = 0; hh < 128; ++hh) {
        float wv = W[hh * 128 + t];
#pragma unroll
        for (int j = 0; j < 8; ++j) acc[j] += s_x[j * 128 + hh] * wv;
    }
#pragma unroll
    for (int j = 0; j < 8; ++j)
        w1t[(long)(r0 + j) * 128 + t] = acc[j];
}

// final gno11 epilogue: v_up1 = relu(acc/deg + w1t) in place; also zero v_down0
__global__ __launch_bounds__(256) void epi11_kernel(
    float* __restrict__ acc, const int* __restrict__ rowptr,
    const float* __restrict__ w1t, int N,
    float* __restrict__ vd0, long n00)
{
    long idx = (long)blockIdx.x * 256 + threadIdx.x;
    if (idx < n00) vd0[idx] = 0.f;
    if (idx >= (long)N * 128) return;
    int d = (int)(idx >> 7);
    float deg = (float)(rowptr[d + 1] - rowptr[d]);
    acc[idx] = fmaxf(acc[idx] / fmaxf(deg, 1.f) + w1t[idx], 0.f);
}

// final epilogue + projection; add1 = acc00 RAW (divided here by deg00)
__global__ __launch_bounds__(128) void epi_proj_kernel(
    const float* __restrict__ acc, const int* __restrict__ rowptr,
    const float* __restrict__ add0,
    const float* __restrict__ add1, const int* __restrict__ rp00,
    const float* __restrict__ projw, const float* __restrict__ projb,
    float* __restrict__ fout, int N)
{
    const int d = blockIdx.x, t = threadIdx.x;
    float deg  = (float)(rowptr[d + 1] - rowptr[d]);
    float dg00 = (float)(rp00[d + 1] - rp00[d]);
    long o = (long)d * 128 + t;
    float res = fmaxf(acc[o] / fmaxf(deg, 1.f) + add0[o] + add1[o] / fmaxf(dg00, 1.f), 0.f);
    float p0 = res * projw[t * 3 + 0];
    float p1 = res * projw[t * 3 + 1];
    float p2 = res * projw[t * 3 + 2];
#pragma unroll
    for (int off = 32; off > 0; off >>= 1) {
        p0 += __shfl_down(p0, off);
        p1 += __shfl_down(p1, off);
        p2 += __shfl_down(p2, off);
    }
    __shared__ float sred[6];
    if ((t & 63) == 0) { int w = t >> 6; sred[w * 3 + 0] = p0; sred[w * 3 + 1] = p1; sred[w * 3 + 2] = p2; }
    __syncthreads();
    if (t < 3) fout[d * 3 + t] = sred[t] + sred[3 + t] + projb[t];
}

extern "C" void kernel_launch(void* const* d_in, const int* in_sizes, int n_in,
                              void* d_out, int out_size, void* d_ws, size_t ws_size,
                              hipStream_t stream)
{
    const float* coords  = (const float*)d_in[0];
    const float* samples = (const float*)d_in[1];
    const float* lift_w  = (const float*)d_in[3];
    const float* lift_b  = (const float*)d_in[4];
    const float* proj_w  = (const float*)d_in[5];
    const float* proj_b  = (const float*)d_in[6];
    const float* W0_w    = (const float*)d_in[7];
    const float* W0_b    = (const float*)d_in[8];
    const float* W1_w    = (const float*)d_in[9];
    const float* W1_b    = (const float*)d_in[10];
    const float *gw1[4], *gb1[4], *gw2[4], *gb2[4];   // 0=gk00,1=gk01,2=gk10,3=gk11
    for (int g = 0; g < 4; ++g) {
        gw1[g] = (const float*)d_in[11 + 4 * g + 0];
        gb1[g] = (const float*)d_in[11 + 4 * g + 1];
        gw2[g] = (const float*)d_in[11 + 4 * g + 2];
        gb2[g] = (const float*)d_in[11 + 4 * g + 3];
    }
    const int* es[4]; const int* ed[4]; int E[4];
    for (int g = 0; g < 4; ++g) {
        es[g] = (const int*)d_in[27 + 2 * g];
        ed[g] = (const int*)d_in[27 + 2 * g + 1];
        E[g]  = in_sizes[27 + 2 * g];
    }

    const int N0 = in_sizes[0] / 2;     // 8192
    const int N1 = (N0 + 1) / 2;        // 4096

    float* ws = (float*)d_ws;
    float* v_down0 = ws;                              // N0*128 (acc10 later)
    float* w0term  = v_down0 + (size_t)N0 * 128;      // N0*128
    float* gno00o  = w0term  + (size_t)N0 * 128;      // N0*128 (acc00, stays raw)
    float* gno01b  = gno00o  + (size_t)N0 * 128;      // N1*128 (acc01, stays raw)
    float* v_down1 = gno01b  + (size_t)N1 * 128;      // N1*128
    float* w1term  = v_down1 + (size_t)N1 * 128;      // N1*128
    float* v_up1   = w1term  + (size_t)N1 * 128;      // N1*128 (acc11 in place)
    short* w2pack  = (short*)(v_up1 + (size_t)N1 * 128);  // 4*8192 bf16
    int*   rp      = (int*)(w2pack + 4 * 8192);
    int* rp00 = rp;                // N0+1
    int* rp01 = rp00 + (N0 + 1);   // N1+1
    int* rp10 = rp01 + (N1 + 1);   // N0+1
    int* rp11 = rp10 + (N0 + 1);   // N1+1

    const long n00 = (long)N0 * 128, n11 = (long)N1 * 128;

    // ---- fused prep: zero(acc00+acc01) + pack_w2 + rowptr x4 + lift/W0 matmul
    {
        int maxE = E[0];
        for (int g = 1; g < 4; ++g) maxE = max(maxE, E[g]);
        PrepArgs A;
        A.zbase = gno00o; A.zn4 = (n00 + n11) / 4;
        for (int g = 0; g < 4; ++g) A.w2s[g] = gw2[g];
        A.w2pack = w2pack;
        A.edst[0] = ed[0]; A.edst[1] = ed[1]; A.edst[2] = ed[2]; A.edst[3] = ed[3];
        A.E[0] = E[0]; A.E[1] = E[1]; A.E[2] = E[2]; A.E[3] = E[3];
        A.N[0] = N0; A.N[1] = N1; A.N[2] = N0; A.N[3] = N1;
        A.rowptr[0] = rp00; A.rowptr[1] = rp01; A.rowptr[2] = rp10; A.rowptr[3] = rp11;
        A.rbPer = (maxE + 255) / 256;
        A.samples = samples; A.LW = lift_w; A.Lb = lift_b; A.W0 = W0_w; A.W0b = W0_b;
        A.vout = v_down0; A.w0t = w0term;
        A.zb = (int)((A.zn4 + 255) / 256);
        int grid = A.zb + 16 + 4 * A.rbPer + N0 / 16;
        prep_kernel<<<grid, 256, 0, stream>>>(A);
    }

    GnoP P00 = {v_down0, es[0], ed[0], gw1[0], gb1[0], w2pack + 0 * 8192, gb2[0], gno00o, E[0], 1, 1, 0};
    GnoP P01 = {v_down0, es[1], ed[1], gw1[1], gb1[1], w2pack + 1 * 8192, gb2[1], gno01b, E[1], 2, 1, 0};
    GnoP P11 = {v_down1, es[3], ed[3], gw1[3], gb1[3], w2pack + 3 * 8192, gb2[3], v_up1,  E[3], 2, 2, 0};
    GnoP P10 = {v_up1,   es[2], ed[2], gw1[2], gb1[2], w2pack + 2 * 8192, gb2[2], v_down0, E[2], 1, 2, 0};

    // gno00 + gno01 merged (both read v_down0)
    {
        int tA = (E[0] + TILE - 1) / TILE, tB = (E[1] + TILE - 1) / TILE;
        gno_edge_kernel<<<tA + tB, 128, 0, stream>>>(coords, N0, P00, P01, tA);
    }

    for (int it = 0; it < 3; ++it) {
        relu_mm_kernel<<<N1 / 8, 128, 0, stream>>>(
            gno01b, rp01, (it == 0) ? nullptr : v_up1, rp11, w1term, W1_w, W1_b,
            v_down1, (it == 0) ? v_up1 : nullptr, N1);
        int tt = (E[3] + TILE - 1) / TILE;
        gno_edge_kernel<<<tt, 128, 0, stream>>>(coords, N0, P11, P11, tt);
    }
    // v_up1 final epilogue + zero acc10 (v_down0)
    epi11_kernel<<<(int)((n00 + 255) / 256), 256, 0, stream>>>(
        v_up1, rp11, w1term, N1, v_down0, n00);

    {
        int tt = (E[2] + TILE - 1) / TILE;
        gno_edge_kernel<<<tt, 128, 0, stream>>>(coords, N0, P10, P10, tt);
    }
    epi_proj_kernel<<<N0, 128, 0, stream>>>(v_down0, rp10, w0term,
                                            gno00o, rp00,
                                            proj_w, proj_b, (float*)d_out, N0);
}

// Round 15
// 343.386 us; speedup vs baseline: 1.1044x; 1.1044x over previous
//
#include <hip/hip_runtime.h>
#include <hip/hip_bf16.h>

typedef __attribute__((ext_vector_type(8))) short s8;   // 8 bf16 = 4 VGPRs
typedef __attribute__((ext_vector_type(4))) float f4;

#define TILE 128

// gelu tanh-approx (JAX approximate=True), exp2-folded
__device__ __forceinline__ float gelu_fast(float x) {
    float x2 = x * x;
    float k2 = x * fmaf(x2, 0.10294326f, 2.30220819f);
    float e  = __builtin_amdgcn_exp2f(k2);
    float r  = __builtin_amdgcn_rcpf(e + 1.f);
    return fmaf(-x, r, x);
}

// round-half-up f32->bf16 pair pack: 3 VALU [numerics validated R10-R14]
__device__ __forceinline__ unsigned pack_bf16x2_fast(float a, float b) {
    unsigned ua = __builtin_bit_cast(unsigned, a) + 0x8000u;
    unsigned ub = __builtin_bit_cast(unsigned, b) + 0x8000u;
    return __builtin_amdgcn_perm(ub, ua, 0x07060302u);
}

__device__ __forceinline__ short f2bf_bits(float v) {
    __hip_bfloat16 b = __float2bfloat16(v);
    return *(short*)&b;
}

// ---------------- fused prep: zero + pack_w2 + rowptr x4 + lift/W0 matmul ----
struct PrepArgs {
    float* zbase; long zn4;                       // zero range (f4 units)
    const float* w2s[4]; short* w2pack;           // pack
    const int* edst[4]; int E[4]; int N[4]; int* rowptr[4]; int rbPer;
    const float *samples, *LW, *Lb, *W0, *W0b;    // lift + W0 matmul
    float *vout, *w0t;
    int zb;                                       // zero block count
};

__global__ __launch_bounds__(256) void prep_kernel(PrepArgs A) {
    __shared__ float s_x[16 * 128];
    int bid = blockIdx.x;
    const int t = threadIdx.x;
    if (bid < A.zb) {                     // ---- zero acc00+acc01
        long i = (long)bid * 256 + t;
        if (i < A.zn4) { f4 z = {0.f, 0.f, 0.f, 0.f}; *(f4*)&A.zbase[i * 4] = z; }
        return;
    }
    bid -= A.zb;
    if (bid < 16) {                       // ---- pack w2 (graph = bid>>2, T = bid&3)
        if (t < 128) {
            const int g = bid >> 2, T = bid & 3;
            const float* w2 = A.w2s[g];
            short* dst = A.w2pack + (size_t)g * 8192;
            const int w = t >> 6, lane = t & 63, q = (lane >> 4), n = lane & 15;
#pragma unroll
            for (int s = 0; s < 2; ++s)
#pragma unroll
                for (int j = 0; j < 8; ++j) {
                    int k  = s * 32 + q * 8 + j;
                    int ch = 64 * w + 4 * n + T;
                    dst[((((w * 4 + T) * 2 + s) * 64) + lane) * 8 + j] =
                        f2bf_bits(w2[k * 128 + ch]);
                }
        }
        return;
    }
    bid -= 16;
    if (bid < 4 * A.rbPer) {              // ---- rowptr for 4 graphs
        const int g = bid / A.rbPer;
        const int i = (bid % A.rbPer) * 256 + t;
        const int* ed = A.edst[g]; const int E = A.E[g]; const int N = A.N[g];
        int* rp = A.rowptr[g];
        if (i < E) {
            int dd = ed[i];
            int p  = (i == 0) ? -1 : ed[i - 1];
            for (int r = p + 1; r <= dd; ++r) rp[r] = i;
            if (i == E - 1)
                for (int r = dd + 1; r <= N; ++r) rp[r] = E;
        }
        return;
    }
    bid -= 4 * A.rbPer;
    // ---- lift + W0 matmul, 16 rows per block, 256 threads
    {
        const int r0 = bid * 16;
        const int col = t & 127, half = t >> 7;
#pragma unroll
        for (int j = 0; j < 8; ++j) {
            int r = r0 + half * 8 + j;
            float s0 = A.samples[r * 3 + 0], s1 = A.samples[r * 3 + 1], s2 = A.samples[r * 3 + 2];
            float v = s0 * A.LW[col] + s1 * A.LW[128 + col] + s2 * A.LW[256 + col] + A.Lb[col];
            s_x[(half * 8 + j) * 128 + col] = v;
            A.vout[(long)r * 128 + col] = v;
        }
        __syncthreads();
        float acc[8];
        const float bc = A.W0b[col];
#pragma unroll
        for (int j = 0; j < 8; ++j) acc[j] = bc;
#pragma unroll 4
        for (int hh = 0; hh < 128; ++hh) {
            float wv = A.W0[hh * 128 + col];
#pragma unroll
            for (int j = 0; j < 8; ++j) acc[j] += s_x[(half * 8 + j) * 128 + hh] * wv;
        }
#pragma unroll
        for (int j = 0; j < 8; ++j)
            A.w0t[(long)(r0 + half * 8 + j) * 128 + col] = acc[j];
    }
}

// ---------------- gno: R13 structure + interior-segment PLAIN STORES ---------
struct GnoP {
    const float* fy;
    const int* esrc;
    const int* edst;
    const float* w1;
    const float* b1;
    const short* w2;
    const float* b2;
    float* acc;
    int E, sx, sy, pad;
};

__device__ __forceinline__ int seg_end(unsigned long long m0, unsigned long long m1, int a) {
    if (a < 64) {
        unsigned long long r = m0 >> a;
        if (r) return a + (int)__builtin_ctzll(r) + 1;
        return 64 + (int)__builtin_ctzll(m1) + 1;
    }
    unsigned long long r = m1 >> (a - 64);
    return a + (int)__builtin_ctzll(r) + 1;
}

// 2-wave blocks, 128 edges/tile, 16-edge windows (R13-exact core).
// Flush: segments fully interior to the tile -> coalesced f4 plain store
// (the wave's sum IS the complete sum); only tile-boundary-carrying segments
// use atomicAdd. Cuts atomic dwords ~60% and write-through amplification.
__global__ __launch_bounds__(128) void gno_edge_kernel(
    const float* __restrict__ coords, int n0, GnoP A, GnoP B, int ntA)
{
    const GnoP P = (blockIdx.x < ntA) ? A : B;
    const int tile = (blockIdx.x < ntA) ? blockIdx.x : blockIdx.x - ntA;
    const int t = threadIdx.x;
    const int w = t >> 6, lane = t & 63, q = lane >> 4, n = lane & 15;
    const int e0 = tile * TILE;
    const int te = min(TILE, P.E - e0);

    __shared__ __align__(16) float s_crd[(TILE + 16) * 4];
    __shared__ int s_off[TILE];
    __shared__ int s_dst[TILE];
    __shared__ unsigned long long s_mask[2];
    __shared__ __align__(16) short s_gb[2][16 * 72];

    {
        int e = min(e0 + t, P.E - 1);
        int sv = P.esrc[e];
        int dv = P.edst[e];
        s_off[t] = sv * 128;
        s_dst[t] = dv;
        f4 c4 = {coords[(long)sv * P.sy], coords[n0 + (long)sv * P.sy],
                 coords[(long)dv * P.sx], coords[n0 + (long)dv * P.sx]};
        *(f4*)&s_crd[t * 4] = c4;
        if (t < 16) *(f4*)&s_crd[(TILE + t) * 4] = c4;
    }

    // does the first/last dst of this tile carry into a neighboring tile?
    const bool carryIn  = (e0 > 0) && (P.edst[e0 - 1] == P.edst[e0]);
    const bool carryOut = (e0 + te < P.E) && (P.edst[e0 + te] == P.edst[e0 + te - 1]);

    const int h0 = 2 * (lane & 31);
    const float wA0 = P.w1[h0],       wA1 = P.w1[h0 + 1];
    const float wB0 = P.w1[64 + h0],  wB1 = P.w1[65 + h0];
    const float wC0 = P.w1[128 + h0], wC1 = P.w1[129 + h0];
    const float wD0 = P.w1[192 + h0], wD1 = P.w1[193 + h0];
    const float b10 = P.b1[h0],       b11 = P.b1[h0 + 1];

    s8 bfrag[4][2];
    const s8* w2f = (const s8*)P.w2;
#pragma unroll
    for (int T = 0; T < 4; ++T)
#pragma unroll
        for (int s = 0; s < 2; ++s)
            bfrag[T][s] = w2f[((w * 4 + T) * 2 + s) * 64 + lane];
    const f4 b2c = *(const f4*)&P.b2[w * 64 + 4 * n];
    f4 b2i[4];
#pragma unroll
    for (int T = 0; T < 4; ++T) { f4 z = {b2c[T], b2c[T], b2c[T], b2c[T]}; b2i[T] = z; }

    const float* fyl = P.fy + (w * 64 + 4 * n);

    __syncthreads();

    {
        int idx = w * 64 + lane;
        bool fl = (idx < te) && (idx == te - 1 || s_dst[idx + 1] != s_dst[idx]);
        unsigned long long m = __ballot(fl);
        if (lane == 0) s_mask[w] = m;
    }
    __syncthreads();
    const unsigned long long m0 = s_mask[0], m1 = s_mask[1];

    int g0 = 0;
    int sa = 0;                       // current segment start (tile-local)
    int b = seg_end(m0, m1, 0);
    f4 fvc[4];
#pragma unroll
    for (int r = 0; r < 4; ++r) {
        int row = q * 4 + r;
        if (row < b) fvc[r] = *(const f4*)&fyl[s_off[row]];
        else { f4 z = {0.f, 0.f, 0.f, 0.f}; fvc[r] = z; }
    }
    f4 accr = {0.f, 0.f, 0.f, 0.f};
    int gbp = 0;
    const int jh = lane >> 5;

    while (true) {
#pragma unroll
        for (int i = 0; i < 4; ++i) {
            int j = 4 * i + 2 * jh + w;
            const f4 crd = *(const f4*)&s_crd[(g0 + j) * 4];
            float x0 = fmaf(crd[0], wA0, fmaf(crd[1], wB0,
                       fmaf(crd[2], wC0, fmaf(crd[3], wD0, b10))));
            float x1 = fmaf(crd[0], wA1, fmaf(crd[1], wB1,
                       fmaf(crd[2], wC1, fmaf(crd[3], wD1, b11))));
            *(unsigned*)&s_gb[gbp][j * 72 + h0] = pack_bf16x2_fast(gelu_fast(x0), gelu_fast(x1));
        }
        __syncthreads();
        const s8 a0 = *(const s8*)&s_gb[gbp][n * 72 + q * 8];
        const s8 a1 = *(const s8*)&s_gb[gbp][n * 72 + q * 8 + 32];
        f4 c[4];
#pragma unroll
        for (int T = 0; T < 4; ++T) {
            f4 z = __builtin_amdgcn_mfma_f32_16x16x32_bf16(a0, bfrag[T][0], b2i[T], 0, 0, 0);
            c[T] = __builtin_amdgcn_mfma_f32_16x16x32_bf16(a1, bfrag[T][1], z, 0, 0, 0);
        }
#pragma unroll
        for (int r = 0; r < 4; ++r)
#pragma unroll
            for (int T = 0; T < 4; ++T)
                accr[T] = fmaf(c[T][r], fvc[r][T], accr[T]);

        int gn = g0 + 16, bn = b;
        const bool endseg = (gn >= b);
        if (endseg) {
            gn = b;
            if (gn < te) bn = seg_end(m0, m1, gn);
            const int dcur = s_dst[g0];
            f4 rv;
#pragma unroll
            for (int T = 0; T < 4; ++T) {
                float v = accr[T];
                v += __shfl_xor(v, 16, 64);
                v += __shfl_xor(v, 32, 64);
                rv[T] = v;
            }
            const bool useAtomic = (sa == 0 && carryIn) || (b >= te && carryOut);
            if (q == 0) {
                float* ap = &P.acc[(long)dcur * 128 + w * 64 + 4 * n];
                if (useAtomic) {
#pragma unroll
                    for (int T = 0; T < 4; ++T) atomicAdd(&ap[T], rv[T]);
                } else {
                    *(f4*)ap = rv;   // complete sum; coalesced 256B per wave
                }
            }
            f4 z = {0.f, 0.f, 0.f, 0.f};
            accr = z;
            sa = b;
        }
        if (gn >= te) break;
#pragma unroll
        for (int r = 0; r < 4; ++r) {
            int row = gn + q * 4 + r;
            if (row < bn) fvc[r] = *(const f4*)&fyl[s_off[row]];
            else { f4 z = {0.f, 0.f, 0.f, 0.f}; fvc[r] = z; }
        }
        g0 = gn; b = bn;
        gbp ^= 1;
    }
}

// fused: base read = gno01b_raw/deg01; u = relu(accu/deg11 + w1t) (rezero accu);
// vd1 = relu(base_mean [+ u]); w1t = vd1 @ W + bias. it0: accu=null, zbuf zeroed.
__global__ __launch_bounds__(128) void relu_mm_kernel(
    const float* __restrict__ base, const int* __restrict__ rp01,
    float* __restrict__ accu, const int* __restrict__ rowptr,
    float* __restrict__ w1t,
    const float* __restrict__ W, const float* __restrict__ bias,
    float* __restrict__ vout, float* __restrict__ zbuf, int R)
{
    const int r0 = blockIdx.x * 8;
    const int t = threadIdx.x;
    __shared__ float s_x[8 * 128];
#pragma unroll
    for (int j = 0; j < 8; ++j) {
        int r = r0 + j;
        long o = (long)r * 128 + t;
        float deg0 = (float)(rp01[r + 1] - rp01[r]);
        float v = base[o] / fmaxf(deg0, 1.f);
        if (accu) {
            float deg = (float)(rowptr[r + 1] - rowptr[r]);
            float u = fmaxf(accu[o] / fmaxf(deg, 1.f) + w1t[o], 0.f);
            v += u;
            accu[o] = 0.f;
        } else if (zbuf) {
            zbuf[o] = 0.f;
        }
        v = fmaxf(v, 0.f);
        s_x[j * 128 + t] = v;
        vout[o] = v;
    }
    __syncthreads();
    float acc[8];
    const float bc = bias[t];
#pragma unroll
    for (int j = 0; j < 8; ++j) acc[j] = bc;
#pragma unroll 4
    for (int hh = 0; hh < 128; ++hh) {
        float wv = W[hh * 128 + t];
#pragma unroll
        for (int j = 0; j < 8; ++j) acc[j] += s_x[j * 128 + hh] * wv;
    }
#pragma unroll
    for (int j = 0; j < 8; ++j)
        w1t[(long)(r0 + j) * 128 + t] = acc[j];
}

// final gno11 epilogue: v_up1 = relu(acc/deg + w1t) in place; also zero v_down0
__global__ __launch_bounds__(256) void epi11_kernel(
    float* __restrict__ acc, const int* __restrict__ rowptr,
    const float* __restrict__ w1t, int N,
    float* __restrict__ vd0, long n00)
{
    long idx = (long)blockIdx.x * 256 + threadIdx.x;
    if (idx < n00) vd0[idx] = 0.f;
    if (idx >= (long)N * 128) return;
    int d = (int)(idx >> 7);
    float deg = (float)(rowptr[d + 1] - rowptr[d]);
    acc[idx] = fmaxf(acc[idx] / fmaxf(deg, 1.f) + w1t[idx], 0.f);
}

// final epilogue + projection; add1 = acc00 RAW (divided here by deg00)
__global__ __launch_bounds__(128) void epi_proj_kernel(
    const float* __restrict__ acc, const int* __restrict__ rowptr,
    const float* __restrict__ add0,
    const float* __restrict__ add1, const int* __restrict__ rp00,
    const float* __restrict__ projw, const float* __restrict__ projb,
    float* __restrict__ fout, int N)
{
    const int d = blockIdx.x, t = threadIdx.x;
    float deg  = (float)(rowptr[d + 1] - rowptr[d]);
    float dg00 = (float)(rp00[d + 1] - rp00[d]);
    long o = (long)d * 128 + t;
    float res = fmaxf(acc[o] / fmaxf(deg, 1.f) + add0[o] + add1[o] / fmaxf(dg00, 1.f), 0.f);
    float p0 = res * projw[t * 3 + 0];
    float p1 = res * projw[t * 3 + 1];
    float p2 = res * projw[t * 3 + 2];
#pragma unroll
    for (int off = 32; off > 0; off >>= 1) {
        p0 += __shfl_down(p0, off);
        p1 += __shfl_down(p1, off);
        p2 += __shfl_down(p2, off);
    }
    __shared__ float sred[6];
    if ((t & 63) == 0) { int w = t >> 6; sred[w * 3 + 0] = p0; sred[w * 3 + 1] = p1; sred[w * 3 + 2] = p2; }
    __syncthreads();
    if (t < 3) fout[d * 3 + t] = sred[t] + sred[3 + t] + projb[t];
}

extern "C" void kernel_launch(void* const* d_in, const int* in_sizes, int n_in,
                              void* d_out, int out_size, void* d_ws, size_t ws_size,
                              hipStream_t stream)
{
    const float* coords  = (const float*)d_in[0];
    const float* samples = (const float*)d_in[1];
    const float* lift_w  = (const float*)d_in[3];
    const float* lift_b  = (const float*)d_in[4];
    const float* proj_w  = (const float*)d_in[5];
    const float* proj_b  = (const float*)d_in[6];
    const float* W0_w    = (const float*)d_in[7];
    const float* W0_b    = (const float*)d_in[8];
    const float* W1_w    = (const float*)d_in[9];
    const float* W1_b    = (const float*)d_in[10];
    const float *gw1[4], *gb1[4], *gw2[4], *gb2[4];   // 0=gk00,1=gk01,2=gk10,3=gk11
    for (int g = 0; g < 4; ++g) {
        gw1[g] = (const float*)d_in[11 + 4 * g + 0];
        gb1[g] = (const float*)d_in[11 + 4 * g + 1];
        gw2[g] = (const float*)d_in[11 + 4 * g + 2];
        gb2[g] = (const float*)d_in[11 + 4 * g + 3];
    }
    const int* es[4]; const int* ed[4]; int E[4];
    for (int g = 0; g < 4; ++g) {
        es[g] = (const int*)d_in[27 + 2 * g];
        ed[g] = (const int*)d_in[27 + 2 * g + 1];
        E[g]  = in_sizes[27 + 2 * g];
    }

    const int N0 = in_sizes[0] / 2;     // 8192
    const int N1 = (N0 + 1) / 2;        // 4096

    float* ws = (float*)d_ws;
    float* v_down0 = ws;                              // N0*128 (acc10 later)
    float* w0term  = v_down0 + (size_t)N0 * 128;      // N0*128
    float* gno00o  = w0term  + (size_t)N0 * 128;      // N0*128 (acc00, stays raw)
    float* gno01b  = gno00o  + (size_t)N0 * 128;      // N1*128 (acc01, stays raw)
    float* v_down1 = gno01b  + (size_t)N1 * 128;      // N1*128
    float* w1term  = v_down1 + (size_t)N1 * 128;      // N1*128
    float* v_up1   = w1term  + (size_t)N1 * 128;      // N1*128 (acc11 in place)
    short* w2pack  = (short*)(v_up1 + (size_t)N1 * 128);  // 4*8192 bf16
    int*   rp      = (int*)(w2pack + 4 * 8192);
    int* rp00 = rp;                // N0+1
    int* rp01 = rp00 + (N0 + 1);   // N1+1
    int* rp10 = rp01 + (N1 + 1);   // N0+1
    int* rp11 = rp10 + (N0 + 1);   // N1+1

    const long n00 = (long)N0 * 128, n11 = (long)N1 * 128;

    // ---- fused prep: zero(acc00+acc01) + pack_w2 + rowptr x4 + lift/W0 matmul
    {
        int maxE = E[0];
        for (int g = 1; g < 4; ++g) maxE = max(maxE, E[g]);
        PrepArgs A;
        A.zbase = gno00o; A.zn4 = (n00 + n11) / 4;
        for (int g = 0; g < 4; ++g) A.w2s[g] = gw2[g];
        A.w2pack = w2pack;
        A.edst[0] = ed[0]; A.edst[1] = ed[1]; A.edst[2] = ed[2]; A.edst[3] = ed[3];
        A.E[0] = E[0]; A.E[1] = E[1]; A.E[2] = E[2]; A.E[3] = E[3];
        A.N[0] = N0; A.N[1] = N1; A.N[2] = N0; A.N[3] = N1;
        A.rowptr[0] = rp00; A.rowptr[1] = rp01; A.rowptr[2] = rp10; A.rowptr[3] = rp11;
        A.rbPer = (maxE + 255) / 256;
        A.samples = samples; A.LW = lift_w; A.Lb = lift_b; A.W0 = W0_w; A.W0b = W0_b;
        A.vout = v_down0; A.w0t = w0term;
        A.zb = (int)((A.zn4 + 255) / 256);
        int grid = A.zb + 16 + 4 * A.rbPer + N0 / 16;
        prep_kernel<<<grid, 256, 0, stream>>>(A);
    }

    GnoP P00 = {v_down0, es[0], ed[0], gw1[0], gb1[0], w2pack + 0 * 8192, gb2[0], gno00o, E[0], 1, 1, 0};
    GnoP P01 = {v_down0, es[1], ed[1], gw1[1], gb1[1], w2pack + 1 * 8192, gb2[1], gno01b, E[1], 2, 1, 0};
    GnoP P11 = {v_down1, es[3], ed[3], gw1[3], gb1[3], w2pack + 3 * 8192, gb2[3], v_up1,  E[3], 2, 2, 0};
    GnoP P10 = {v_up1,   es[2], ed[2], gw1[2], gb1[2], w2pack + 2 * 8192, gb2[2], v_down0, E[2], 1, 2, 0};

    // gno00 + gno01 merged (both read v_down0)
    {
        int tA = (E[0] + TILE - 1) / TILE, tB = (E[1] + TILE - 1) / TILE;
        gno_edge_kernel<<<tA + tB, 128, 0, stream>>>(coords, N0, P00, P01, tA);
    }

    for (int it = 0; it < 3; ++it) {
        relu_mm_kernel<<<N1 / 8, 128, 0, stream>>>(
            gno01b, rp01, (it == 0) ? nullptr : v_up1, rp11, w1term, W1_w, W1_b,
            v_down1, (it == 0) ? v_up1 : nullptr, N1);
        int tt = (E[3] + TILE - 1) / TILE;
        gno_edge_kernel<<<tt, 128, 0, stream>>>(coords, N0, P11, P11, tt);
    }
    // v_up1 final epilogue + zero acc10 (v_down0)
    epi11_kernel<<<(int)((n00 + 255) / 256), 256, 0, stream>>>(
        v_up1, rp11, w1term, N1, v_down0, n00);

    {
        int tt = (E[2] + TILE - 1) / TILE;
        gno_edge_kernel<<<tt, 128, 0, stream>>>(coords, N0, P10, P10, tt);
    }
    epi_proj_kernel<<<N0, 128, 0, stream>>>(v_down0, rp10, w0term,
                                            gno00o, rp00,
                                            proj_w, proj_b, (float*)d_out, N0);
}